// Round 8
// baseline (152.690 us; speedup 1.0000x reference)
//
#include <hip/hip_runtime.h>

#define NB 8
#define KK 20
#define XD 224
#define YD 224
#define NPIX (XD*YD)        // 50176
#define TILE 16
#define NT 14               // 224/16
#define TW 26               // TILE + 2*5 halo
#define NOFF 31
#define NKTOT (NB*KK)       // 160
#define NTILES (NT*NT)      // 196
#define NPH 2               // k-phases (10 k's each, no tail)
#define KPH 10
#define NCOMP 6             // partials per (n,k): pa, psq, px0, px1, px2, pseg
#define PSTRIDE (NB*KK*NCOMP)   // 960 floats per tile row

namespace {
// offsets with sqrt(dm^2+dn^2) >= 5, dm,dn in [-5,4] (faithful to source)
constexpr int DM[NOFF] = {
  -5,-5,-5,-5,-5,-5,-5,-5,-5,-5,
  -4,-4,-4,-4,-4,
  -3,-3,-3,
  -2,-1, 0, 1, 2,
   3, 3, 3,
   4, 4, 4, 4, 4};
constexpr int DN[NOFF] = {
  -5,-4,-3,-2,-1, 0, 1, 2, 3, 4,
  -5,-4,-3, 3, 4,
  -5,-4, 4,
  -5,-5,-5,-5,-5,
  -5,-4, 4,
  -5,-4,-3, 3, 4};

constexpr int ROFXI[NOFF] = {
  (DM[0]+5)*TW+(DN[0]+5),  (DM[1]+5)*TW+(DN[1]+5),  (DM[2]+5)*TW+(DN[2]+5),
  (DM[3]+5)*TW+(DN[3]+5),  (DM[4]+5)*TW+(DN[4]+5),  (DM[5]+5)*TW+(DN[5]+5),
  (DM[6]+5)*TW+(DN[6]+5),  (DM[7]+5)*TW+(DN[7]+5),  (DM[8]+5)*TW+(DN[8]+5),
  (DM[9]+5)*TW+(DN[9]+5),  (DM[10]+5)*TW+(DN[10]+5),(DM[11]+5)*TW+(DN[11]+5),
  (DM[12]+5)*TW+(DN[12]+5),(DM[13]+5)*TW+(DN[13]+5),(DM[14]+5)*TW+(DN[14]+5),
  (DM[15]+5)*TW+(DN[15]+5),(DM[16]+5)*TW+(DN[16]+5),(DM[17]+5)*TW+(DN[17]+5),
  (DM[18]+5)*TW+(DN[18]+5),(DM[19]+5)*TW+(DN[19]+5),(DM[20]+5)*TW+(DN[20]+5),
  (DM[21]+5)*TW+(DN[21]+5),(DM[22]+5)*TW+(DN[22]+5),(DM[23]+5)*TW+(DN[23]+5),
  (DM[24]+5)*TW+(DN[24]+5),(DM[25]+5)*TW+(DN[25]+5),(DM[26]+5)*TW+(DN[26]+5),
  (DM[27]+5)*TW+(DN[27]+5),(DM[28]+5)*TW+(DN[28]+5),(DM[29]+5)*TW+(DN[29]+5),
  (DM[30]+5)*TW+(DN[30]+5)};
constexpr float COSC[NOFF] = {
  (DM[0]*DM[0]+DN[0]*DN[0])/40.0f,   (DM[1]*DM[1]+DN[1]*DN[1])/40.0f,
  (DM[2]*DM[2]+DN[2]*DN[2])/40.0f,   (DM[3]*DM[3]+DN[3]*DN[3])/40.0f,
  (DM[4]*DM[4]+DN[4]*DN[4])/40.0f,   (DM[5]*DM[5]+DN[5]*DN[5])/40.0f,
  (DM[6]*DM[6]+DN[6]*DN[6])/40.0f,   (DM[7]*DM[7]+DN[7]*DN[7])/40.0f,
  (DM[8]*DM[8]+DN[8]*DN[8])/40.0f,   (DM[9]*DM[9]+DN[9]*DN[9])/40.0f,
  (DM[10]*DM[10]+DN[10]*DN[10])/40.0f,(DM[11]*DM[11]+DN[11]*DN[11])/40.0f,
  (DM[12]*DM[12]+DN[12]*DN[12])/40.0f,(DM[13]*DM[13]+DN[13]*DN[13])/40.0f,
  (DM[14]*DM[14]+DN[14]*DN[14])/40.0f,(DM[15]*DM[15]+DN[15]*DN[15])/40.0f,
  (DM[16]*DM[16]+DN[16]*DN[16])/40.0f,(DM[17]*DM[17]+DN[17]*DN[17])/40.0f,
  (DM[18]*DM[18]+DN[18]*DN[18])/40.0f,(DM[19]*DM[19]+DN[19]*DN[19])/40.0f,
  (DM[20]*DM[20]+DN[20]*DN[20])/40.0f,(DM[21]*DM[21]+DN[21]*DN[21])/40.0f,
  (DM[22]*DM[22]+DN[22]*DN[22])/40.0f,(DM[23]*DM[23]+DN[23]*DN[23])/40.0f,
  (DM[24]*DM[24]+DN[24]*DN[24])/40.0f,(DM[25]*DM[25]+DN[25]*DN[25])/40.0f,
  (DM[26]*DM[26]+DN[26]*DN[26])/40.0f,(DM[27]*DM[27]+DN[27]*DN[27])/40.0f,
  (DM[28]*DM[28]+DN[28]*DN[28])/40.0f,(DM[29]*DM[29]+DN[29]*DN[29])/40.0f,
  (DM[30]*DM[30]+DN[30]*DN[30])/40.0f};
}

// ---------- K1: main tile kernel, 2 k-phases x 10 k's, stats-free.
// assocV decomposed (pv = npix*PSQ - 2*S.PX + s2*PSEG) so global x-stats are
// NOT needed here -> stats kernels eliminated (R7: 5 dispatches had ~74us of
// boundary overhead invariant to epilogue shape). Emits 6 partials per (n,k)
// + 4 per-tile x-stats; single final kernel composes everything.
__global__ __launch_bounds__(256, 4)
void ncuts_main(const float* __restrict__ seg, const float* __restrict__ x,
                float* __restrict__ part6, float* __restrict__ xstat) {
  __shared__ __align__(16) float sSegA[TW*TW*4];   // [pix][k0..3],  10816 B
  __shared__ __align__(16) float sSegB[TW*TW*4];   // [pix][k4..7],  10816 B
  __shared__ __align__(16) float sSegC[TW*TW*2];   // [pix][k8..9],   5408 B
  __shared__ __align__(16) float sXi[TW*TW*4];     // [pix][{x0,x1,x2,0}], 10816 B
  __shared__ float sRed[4][2*KPH*NCOMP];           // [wave][120], 1920 B
  __shared__ float sRedX[4][4];                    // 64 B

  const int t = threadIdx.x;
  const int lane = t & 63, wv = t >> 6;
  const int tx = t & 15, ty = t >> 4;
  const int tcx = blockIdx.x, tcy = blockIdx.y, n = blockIdx.z;
  const int r0 = tcy * TILE - 5, c0 = tcx * TILE - 5;

  // ---- stage xi packed float4 (676 pixels) ----
  const float* xb = x + n * 3 * NPIX;
  for (int e = t; e < TW * TW; e += 256) {
    const int rr = e / TW, cc = e - rr * TW;
    const int gr = r0 + rr, gc = c0 + cc;
    float v0 = 0.f, v1 = 0.f, v2 = 0.f;
    if ((unsigned)gr < XD && (unsigned)gc < YD) {
      const int g = gr * YD + gc;
      v0 = xb[g]; v1 = xb[NPIX + g]; v2 = xb[2 * NPIX + g];
    }
    *reinterpret_cast<float4*>(&sXi[e * 4]) = make_float4(v0, v1, v2, 0.f);
  }

  // ---- phase-invariant pixel-slot decomposition for seg staging ----
  const float* sb = seg + n * KK * NPIX;
  const float* psb[3]; bool pok[3];
  #pragma unroll
  for (int s = 0; s < 3; ++s) {
    const int p = t + s * 256;
    const int rr = p / TW, cc = p - rr * TW;
    const int gr = r0 + rr, gc = c0 + cc;
    pok[s] = (p < TW * TW) && ((unsigned)gr < XD) && ((unsigned)gc < YD);
    psb[s] = sb + (gr * YD + gc);   // only dereferenced when pok[s]
  }

  const int xib = ty * TW + tx;                  // corner-based pixel index
  const int cen = xib + (5 * TW + 5);

  // 4-stream packed butterfly: lane l (l<4) ends holding block-wide... wave-wide
  // sum of stream l (verified mapping from R3-R7 epilogues).
  auto RED4 = [&](float v0, float v1, float v2, float v3) -> float {
    float s0 = (lane & 1) ? v1 : v0;
    float g0 = (lane & 1) ? v0 : v1;
    s0 += __shfl_xor(g0, 1, 64);
    float s1 = (lane & 1) ? v3 : v2;
    float g1 = (lane & 1) ? v2 : v3;
    s1 += __shfl_xor(g1, 1, 64);
    float cv = (lane & 2) ? s1 : s0;
    float gv = (lane & 2) ? s0 : s1;
    cv += __shfl_xor(gv, 2, 64);
    cv += __shfl_xor(cv, 4, 64);
    cv += __shfl_xor(cv, 8, 64);
    cv += __shfl_xor(cv, 16, 64);
    cv += __shfl_xor(cv, 32, 64);
    return cv;
  };

  __syncthreads();   // xi staging done
  const float4 xc = *reinterpret_cast<const float4*>(&sXi[cen * 4]);
  const float xc0 = xc.x, xc1 = xc.y, xc2 = xc.z;
  const float sqc = xc0*xc0 + xc1*xc1 + xc2*xc2;

  // per-tile x-stats over the 16x16 interior (each global pixel exactly once)
  {
    const float cvX = RED4(xc0, xc1, xc2, sqc);
    if (lane < 4) sRedX[wv][lane] = cvX;
  }

  #pragma unroll 1
  for (int p = 0; p < NPH; ++p) {
    const int kbase = p * KPH;

    __syncthreads();   // prior phase's sSeg reads done

    // stage this phase's 10 k-planes: one pixel per thread-slot,
    // 10 coalesced global loads, b128+b128+b64 conflict-free LDS writes.
    #pragma unroll
    for (int s = 0; s < 3; ++s) {
      const int pix = t + s * 256;
      if (pix < TW * TW) {
        float v[KPH];
        #pragma unroll
        for (int ks = 0; ks < KPH; ++ks) v[ks] = 0.f;
        if (pok[s]) {
          #pragma unroll
          for (int ks = 0; ks < KPH; ++ks) v[ks] = psb[s][(kbase + ks) * NPIX];
        }
        *reinterpret_cast<float4*>(&sSegA[pix * 4]) = make_float4(v[0], v[1], v[2], v[3]);
        *reinterpret_cast<float4*>(&sSegB[pix * 4]) = make_float4(v[4], v[5], v[6], v[7]);
        *reinterpret_cast<float2*>(&sSegC[pix * 2]) = make_float2(v[8], v[9]);
      }
    }
    __syncthreads();

    float acc[KPH];
    #pragma unroll
    for (int k = 0; k < KPH; ++k) acc[k] = 0.f;

    // unroll 2 (NOT full): full unroll spilled to scratch in R1 (646MB write traffic)
    #pragma unroll 2
    for (int o = 0; o < NOFF; ++o) {
      const int rof = ROFXI[o];
      const float4 xs = *reinterpret_cast<const float4*>(&sXi[(xib + rof) * 4]);
      const float d0 = xc0 - xs.x, d1 = xc1 - xs.y, d2 = xc2 - xs.z;
      const float dd = fmaf(d0, d0, fmaf(d1, d1, d2 * d2));
      // w = cosc * sqrt(dd): dd * rsqrt(dd) avoids the OCML sqrt sequence.
      const float w = COSC[o] * dd * __frsqrt_rn(fmaxf(dd, 1e-30f));
      const float4 q0 = *reinterpret_cast<const float4*>(&sSegA[(xib + rof) * 4]);
      const float4 q1 = *reinterpret_cast<const float4*>(&sSegB[(xib + rof) * 4]);
      const float2 q2 = *reinterpret_cast<const float2*>(&sSegC[(xib + rof) * 2]);
      acc[0] = fmaf(w, q0.x, acc[0]); acc[1] = fmaf(w, q0.y, acc[1]);
      acc[2] = fmaf(w, q0.z, acc[2]); acc[3] = fmaf(w, q0.w, acc[3]);
      acc[4] = fmaf(w, q1.x, acc[4]); acc[5] = fmaf(w, q1.y, acc[5]);
      acc[6] = fmaf(w, q1.z, acc[6]); acc[7] = fmaf(w, q1.w, acc[7]);
      acc[8] = fmaf(w, q2.x, acc[8]); acc[9] = fmaf(w, q2.y, acc[9]);
    }

    // center seg for this phase's k's
    const float4 c0v = *reinterpret_cast<const float4*>(&sSegA[cen * 4]);
    const float4 c1v = *reinterpret_cast<const float4*>(&sSegB[cen * 4]);
    const float2 c2v = *reinterpret_cast<const float2*>(&sSegC[cen * 2]);
    const float segc[KPH] = {c0v.x, c0v.y, c0v.z, c0v.w,
                             c1v.x, c1v.y, c1v.z, c1v.w, c2v.x, c2v.y};

    // 6 streams per k: {pa, psq, px0, px1, px2, pseg}; 60 scalars per phase,
    // 15 RED4 passes. idx i -> k=i/6, c=i%6 (static after unroll).
    auto VAL = [&](int i) -> float {
      const int k = i / NCOMP, c = i % NCOMP;
      const float s = segc[k];
      return c == 0 ? s * acc[k]
           : c == 1 ? s * sqc
           : c == 2 ? s * xc0
           : c == 3 ? s * xc1
           : c == 4 ? s * xc2
           : s;
    };
    #pragma unroll
    for (int jq = 0; jq < (KPH * NCOMP) / 4; ++jq) {
      const int i0 = 4 * jq;
      const float cv = RED4(VAL(i0), VAL(i0 + 1), VAL(i0 + 2), VAL(i0 + 3));
      if (lane < 4) sRed[wv][p * (KPH * NCOMP) + i0 + lane] = cv;
    }
  }

  __syncthreads();
  const int tile = tcy * NT + tcx;
  // sRed slot g (0..119): k = g/6, c = g%6 globally (phase p covers [60p,60p+60)).
  if (t < 2 * KPH * NCOMP) {
    const float s = sRed[0][t] + sRed[1][t] + sRed[2][t] + sRed[3][t];
    part6[tile * PSTRIDE + n * (KK * NCOMP) + t] = s;   // coalesced 120-float burst
  } else if (t < 2 * KPH * NCOMP + 4) {
    const int j = t - 2 * KPH * NCOMP;
    xstat[(n * NTILES + tile) * 4 + j] =
        sRedX[0][j] + sRedX[1][j] + sRedX[2][j] + sRedX[3][j];
  }
}

// ---------- K2: single-block finisher: S/s2 from x-stats, compose pv, loss ----------
__global__ void ncuts_final(const float* __restrict__ part6,
                            const float* __restrict__ xstat,
                            float* __restrict__ out) {
  __shared__ float sXr[32][8];
  __shared__ float sS[NB][4];       // S0,S1,S2,s2 per batch
  __shared__ float sP[PSTRIDE];     // 960 per-(n,k,c) totals
  __shared__ float red[256];
  const int t = threadIdx.x;        // 1024 threads

  // phase A: tile-sum of the 6 partials (coalesced: consecutive t -> consecutive addr)
  float s6 = 0.f;
  if (t < PSTRIDE) {
    for (int j = 0; j < NTILES; ++j) s6 += part6[j * PSTRIDE + t];
  }
  // phase A': x-stat partial sums (32 combos x 8 sub-chunks)
  if (t < 256) {
    const int combo = t >> 3, sub = t & 7;
    const int n = combo >> 2, j = combo & 3;
    float s = 0.f;
    for (int i = sub; i < NTILES; i += 8) s += xstat[(n * NTILES + i) * 4 + j];
    sXr[combo][sub] = s;
  }
  if (t < PSTRIDE) sP[t] = s6;
  __syncthreads();
  if (t < 32) {
    float s = 0.f;
    #pragma unroll
    for (int u = 0; u < 8; ++u) s += sXr[t][u];
    sS[t >> 2][t & 3] = s;
  }
  __syncthreads();

  // phase B: per-(n,k) ratio
  float r = 0.f;
  if (t < NKTOT) {
    const int n = t / KK;
    const float pa   = sP[t * 6 + 0];
    const float psq  = sP[t * 6 + 1];
    const float px0  = sP[t * 6 + 2];
    const float px1  = sP[t * 6 + 3];
    const float px2  = sP[t * 6 + 4];
    const float pseg = sP[t * 6 + 5];
    const float S0 = sS[n][0], S1 = sS[n][1], S2 = sS[n][2], s2n = sS[n][3];
    const float pv = 50176.f * psq
                   - 2.f * (S0 * px0 + S1 * px1 + S2 * px2)
                   + s2n * pseg;
    r = pa / pv;
  }
  if (t < 256) red[t] = r;
  __syncthreads();
  for (int s = 128; s > 0; s >>= 1) {
    if (t < s) red[t] += red[t + s];
    __syncthreads();
  }
  if (t == 0) out[0] = (float)NKTOT - red[0];
}

extern "C" void kernel_launch(void* const* d_in, const int* in_sizes, int n_in,
                              void* d_out, int out_size, void* d_ws, size_t ws_size,
                              hipStream_t stream) {
  const float* seg = (const float*)d_in[0];
  const float* x   = (const float*)d_in[1];
  float* ws    = (float*)d_ws;
  float* part6 = ws;                            // 196*960 = 188160 floats
  float* xstat = ws + NTILES * PSTRIDE;         // 8*196*4 = 6272 floats

  dim3 grid(NT, NT, NB);
  ncuts_main<<<grid, 256, 0, stream>>>(seg, x, part6, xstat);
  ncuts_final<<<1, 1024, 0, stream>>>(part6, xstat, (float*)d_out);
}

// Round 10
// 132.758 us; speedup vs baseline: 1.1501x; 1.1501x over previous
//
#include <hip/hip_runtime.h>

#define NB 8
#define KK 20
#define XD 224
#define YD 224
#define NPIX (XD*YD)        // 50176
#define TILE 16
#define NT 14               // 224/16
#define TW 25               // TILE + 5 + 4 (offsets span [-5,4]; +5 edge never read)
#define NPIXT (TW*TW)       // 625
#define NOFF 31
#define NKTOT (NB*KK)       // 160
#define NTILES (NT*NT)      // 196
#define NPH 2               // k-phases (10 k's each, no tail)
#define KPH 10
#define SB 32               // stats slices per batch

namespace {
// offsets with sqrt(dm^2+dn^2) >= 5, dm,dn in [-5,4] (faithful to source)
constexpr int DM[NOFF] = {
  -5,-5,-5,-5,-5,-5,-5,-5,-5,-5,
  -4,-4,-4,-4,-4,
  -3,-3,-3,
  -2,-1, 0, 1, 2,
   3, 3, 3,
   4, 4, 4, 4, 4};
constexpr int DN[NOFF] = {
  -5,-4,-3,-2,-1, 0, 1, 2, 3, 4,
  -5,-4,-3, 3, 4,
  -5,-4, 4,
  -5,-5,-5,-5,-5,
  -5,-4, 4,
  -5,-4,-3, 3, 4};

constexpr int ROFXI[NOFF] = {
  (DM[0]+5)*TW+(DN[0]+5),  (DM[1]+5)*TW+(DN[1]+5),  (DM[2]+5)*TW+(DN[2]+5),
  (DM[3]+5)*TW+(DN[3]+5),  (DM[4]+5)*TW+(DN[4]+5),  (DM[5]+5)*TW+(DN[5]+5),
  (DM[6]+5)*TW+(DN[6]+5),  (DM[7]+5)*TW+(DN[7]+5),  (DM[8]+5)*TW+(DN[8]+5),
  (DM[9]+5)*TW+(DN[9]+5),  (DM[10]+5)*TW+(DN[10]+5),(DM[11]+5)*TW+(DN[11]+5),
  (DM[12]+5)*TW+(DN[12]+5),(DM[13]+5)*TW+(DN[13]+5),(DM[14]+5)*TW+(DN[14]+5),
  (DM[15]+5)*TW+(DN[15]+5),(DM[16]+5)*TW+(DN[16]+5),(DM[17]+5)*TW+(DN[17]+5),
  (DM[18]+5)*TW+(DN[18]+5),(DM[19]+5)*TW+(DN[19]+5),(DM[20]+5)*TW+(DN[20]+5),
  (DM[21]+5)*TW+(DN[21]+5),(DM[22]+5)*TW+(DN[22]+5),(DM[23]+5)*TW+(DN[23]+5),
  (DM[24]+5)*TW+(DN[24]+5),(DM[25]+5)*TW+(DN[25]+5),(DM[26]+5)*TW+(DN[26]+5),
  (DM[27]+5)*TW+(DN[27]+5),(DM[28]+5)*TW+(DN[28]+5),(DM[29]+5)*TW+(DN[29]+5),
  (DM[30]+5)*TW+(DN[30]+5)};
constexpr float COSC[NOFF] = {
  (DM[0]*DM[0]+DN[0]*DN[0])/40.0f,   (DM[1]*DM[1]+DN[1]*DN[1])/40.0f,
  (DM[2]*DM[2]+DN[2]*DN[2])/40.0f,   (DM[3]*DM[3]+DN[3]*DN[3])/40.0f,
  (DM[4]*DM[4]+DN[4]*DN[4])/40.0f,   (DM[5]*DM[5]+DN[5]*DN[5])/40.0f,
  (DM[6]*DM[6]+DN[6]*DN[6])/40.0f,   (DM[7]*DM[7]+DN[7]*DN[7])/40.0f,
  (DM[8]*DM[8]+DN[8]*DN[8])/40.0f,   (DM[9]*DM[9]+DN[9]*DN[9])/40.0f,
  (DM[10]*DM[10]+DN[10]*DN[10])/40.0f,(DM[11]*DM[11]+DN[11]*DN[11])/40.0f,
  (DM[12]*DM[12]+DN[12]*DN[12])/40.0f,(DM[13]*DM[13]+DN[13]*DN[13])/40.0f,
  (DM[14]*DM[14]+DN[14]*DN[14])/40.0f,(DM[15]*DM[15]+DN[15]*DN[15])/40.0f,
  (DM[16]*DM[16]+DN[16]*DN[16])/40.0f,(DM[17]*DM[17]+DN[17]*DN[17])/40.0f,
  (DM[18]*DM[18]+DN[18]*DN[18])/40.0f,(DM[19]*DM[19]+DN[19]*DN[19])/40.0f,
  (DM[20]*DM[20]+DN[20]*DN[20])/40.0f,(DM[21]*DM[21]+DN[21]*DN[21])/40.0f,
  (DM[22]*DM[22]+DN[22]*DN[22])/40.0f,(DM[23]*DM[23]+DN[23]*DN[23])/40.0f,
  (DM[24]*DM[24]+DN[24]*DN[24])/40.0f,(DM[25]*DM[25]+DN[25]*DN[25])/40.0f,
  (DM[26]*DM[26]+DN[26]*DN[26])/40.0f,(DM[27]*DM[27]+DN[27]*DN[27])/40.0f,
  (DM[28]*DM[28]+DN[28]*DN[28])/40.0f,(DM[29]*DM[29]+DN[29]*DN[29])/40.0f,
  (DM[30]*DM[30]+DN[30]*DN[30])/40.0f};
}

// ---------- K1a: per-(batch,slice) partial sums over x ----------
__global__ void ncuts_stats1(const float* __restrict__ x, float* __restrict__ part) {
  __shared__ float red[4][4];
  const int b = blockIdx.x;
  const int n = b >> 5, s = b & 31;          // SB = 32
  const int t = threadIdx.x;
  const int lane = t & 63, wv = t >> 6;
  const float* xb = x + n * 3 * NPIX;
  const int base = s * (NPIX / SB);          // 1568 per slice
  float a0 = 0.f, a1 = 0.f, a2 = 0.f, aq = 0.f;
  for (int i = t; i < NPIX / SB; i += 256) {
    const int p = base + i;
    float v0 = xb[p], v1 = xb[NPIX + p], v2 = xb[2 * NPIX + p];
    a0 += v0; a1 += v1; a2 += v2;
    aq = fmaf(v0, v0, fmaf(v1, v1, fmaf(v2, v2, aq)));
  }
  #pragma unroll
  for (int m = 1; m < 64; m <<= 1) {
    a0 += __shfl_xor(a0, m, 64); a1 += __shfl_xor(a1, m, 64);
    a2 += __shfl_xor(a2, m, 64); aq += __shfl_xor(aq, m, 64);
  }
  if (lane == 0) { red[wv][0] = a0; red[wv][1] = a1; red[wv][2] = a2; red[wv][3] = aq; }
  __syncthreads();
  if (t < 4) part[b * 4 + t] = red[0][t] + red[1][t] + red[2][t] + red[3][t];
}

// ---------- K1b: reduce slice partials -> S[n][3], s2[n] ----------
__global__ void ncuts_stats2(const float* __restrict__ part,
                             float* __restrict__ Sv, float* __restrict__ s2v) {
  const int t = threadIdx.x;
  if (t < NB * 4) {
    const int n = t >> 2, val = t & 3;
    float s = 0.f;
    #pragma unroll 4
    for (int i = 0; i < SB; ++i) s += part[(n * SB + i) * 4 + val];
    if (val < 3) Sv[n * 3 + val] = s; else s2v[n] = s;
  }
}

// ---------- K2: main tile kernel, 2 k-phases x 10 k's.
// R8 lesson: dispatch count is free (fixed ~70us bench floor regardless of
// 5 vs 2 kernels); the 6-comp pv decomposition tripled shuffle DS traffic
// and cost +28% -> reverted to precomputed-temp 2-stream form (R7, 58us).
// R9 levers: offset-loop unroll 4 (was 2; DS only ~55% busy -> dependency
// stalls, need more chains in flight) and TW 26->25 (+5 halo edge never read).
__global__ __launch_bounds__(256, 4)
void ncuts_main(const float* __restrict__ seg, const float* __restrict__ x,
                const float* __restrict__ Sv, const float* __restrict__ s2v,
                float* __restrict__ pA, float* __restrict__ pV) {
  __shared__ __align__(16) float sSegA[NPIXT*4];   // [pix][k0..3], 10000 B
  __shared__ __align__(16) float sSegB[NPIXT*4];   // [pix][k4..7], 10000 B
  __shared__ __align__(16) float sSegC[NPIXT*2];   // [pix][k8..9],  5000 B
  __shared__ __align__(16) float sXi[NPIXT*4];     // [pix][{x0,x1,x2,0}], 10000 B
  __shared__ float sRed[4][2*KK];                  // 640 B

  const int t = threadIdx.x;
  const int lane = t & 63, wv = t >> 6;
  const int tx = t & 15, ty = t >> 4;
  const int tcx = blockIdx.x, tcy = blockIdx.y, n = blockIdx.z;
  const int r0 = tcy * TILE - 5, c0 = tcx * TILE - 5;

  // ---- stage xi packed float4 (625 pixels) ----
  const float* xb = x + n * 3 * NPIX;
  for (int e = t; e < NPIXT; e += 256) {
    const int rr = e / TW, cc = e - rr * TW;
    const int gr = r0 + rr, gc = c0 + cc;
    float v0 = 0.f, v1 = 0.f, v2 = 0.f;
    if ((unsigned)gr < XD && (unsigned)gc < YD) {
      const int g = gr * YD + gc;
      v0 = xb[g]; v1 = xb[NPIX + g]; v2 = xb[2 * NPIX + g];
    }
    *reinterpret_cast<float4*>(&sXi[e * 4]) = make_float4(v0, v1, v2, 0.f);
  }

  // ---- phase-invariant pixel-slot decomposition for seg staging ----
  const float* sb = seg + n * KK * NPIX;
  const float* psb[3]; bool pok[3];
  #pragma unroll
  for (int s = 0; s < 3; ++s) {
    const int p = t + s * 256;
    const int rr = p / TW, cc = p - rr * TW;
    const int gr = r0 + rr, gc = c0 + cc;
    pok[s] = (p < NPIXT) && ((unsigned)gr < XD) && ((unsigned)gc < YD);
    psb[s] = sb + (gr * YD + gc);   // only dereferenced when pok[s]
  }

  const int xib = ty * TW + tx;                  // corner-based pixel index
  const int cen = xib + (5 * TW + 5);

  const float S0 = Sv[n*3+0], S1 = Sv[n*3+1], S2 = Sv[n*3+2], s2n = s2v[n];

  __syncthreads();   // xi staging done
  const float4 xc = *reinterpret_cast<const float4*>(&sXi[cen * 4]);
  const float xc0 = xc.x, xc1 = xc.y, xc2 = xc.z;
  const float sqc = xc0*xc0 + xc1*xc1 + xc2*xc2;
  const float temp = 50176.f * sqc - 2.f * (xc0*S0 + xc1*S1 + xc2*S2) + s2n;

  #pragma unroll 1
  for (int p = 0; p < NPH; ++p) {
    const int kbase = p * KPH;

    __syncthreads();   // prior phase's sSeg reads done

    // stage this phase's 10 k-planes: one pixel per thread-slot,
    // 10 coalesced global loads, b128+b128+b64 conflict-free LDS writes.
    #pragma unroll
    for (int s = 0; s < 3; ++s) {
      const int pix = t + s * 256;
      if (pix < NPIXT) {
        float v[KPH];
        #pragma unroll
        for (int ks = 0; ks < KPH; ++ks) v[ks] = 0.f;
        if (pok[s]) {
          #pragma unroll
          for (int ks = 0; ks < KPH; ++ks) v[ks] = psb[s][(kbase + ks) * NPIX];
        }
        *reinterpret_cast<float4*>(&sSegA[pix * 4]) = make_float4(v[0], v[1], v[2], v[3]);
        *reinterpret_cast<float4*>(&sSegB[pix * 4]) = make_float4(v[4], v[5], v[6], v[7]);
        *reinterpret_cast<float2*>(&sSegC[pix * 2]) = make_float2(v[8], v[9]);
      }
    }
    __syncthreads();

    float acc[KPH];
    #pragma unroll
    for (int k = 0; k < KPH; ++k) acc[k] = 0.f;

    // unroll 4: DS pipe only ~55% busy at unroll 2 -> expose 4 independent
    // xi-read -> w -> FMA chains. NOT full unroll (R1: scratch spill disaster).
    #pragma unroll 4
    for (int o = 0; o < NOFF; ++o) {
      const int rof = ROFXI[o];
      const float4 xs = *reinterpret_cast<const float4*>(&sXi[(xib + rof) * 4]);
      const float d0 = xc0 - xs.x, d1 = xc1 - xs.y, d2 = xc2 - xs.z;
      const float dd = fmaf(d0, d0, fmaf(d1, d1, d2 * d2));
      // w = cosc * sqrt(dd): dd * rsqrt(dd) avoids the OCML sqrt sequence.
      const float w = COSC[o] * dd * __frsqrt_rn(fmaxf(dd, 1e-30f));
      const float4 q0 = *reinterpret_cast<const float4*>(&sSegA[(xib + rof) * 4]);
      const float4 q1 = *reinterpret_cast<const float4*>(&sSegB[(xib + rof) * 4]);
      const float2 q2 = *reinterpret_cast<const float2*>(&sSegC[(xib + rof) * 2]);
      acc[0] = fmaf(w, q0.x, acc[0]); acc[1] = fmaf(w, q0.y, acc[1]);
      acc[2] = fmaf(w, q0.z, acc[2]); acc[3] = fmaf(w, q0.w, acc[3]);
      acc[4] = fmaf(w, q1.x, acc[4]); acc[5] = fmaf(w, q1.y, acc[5]);
      acc[6] = fmaf(w, q1.z, acc[6]); acc[7] = fmaf(w, q1.w, acc[7]);
      acc[8] = fmaf(w, q2.x, acc[8]); acc[9] = fmaf(w, q2.y, acc[9]);
    }

    // center seg for this phase's k's
    const float4 c0v = *reinterpret_cast<const float4*>(&sSegA[cen * 4]);
    const float4 c1v = *reinterpret_cast<const float4*>(&sSegB[cen * 4]);
    const float2 c2v = *reinterpret_cast<const float2*>(&sSegC[cen * 2]);
    const float segc[KPH] = {c0v.x, c0v.y, c0v.z, c0v.w,
                             c1v.x, c1v.y, c1v.z, c1v.w, c2v.x, c2v.y};

    // packed butterfly: {pa,pv} x 2 k's per pass, 5 passes per phase.
    #pragma unroll
    for (int pp = 0; pp < KPH / 2; ++pp) {
      const int s0i = 2 * pp, s1i = 2 * pp + 1;
      float pa0 = segc[s0i] * acc[s0i], pv0 = segc[s0i] * temp;
      float pa1 = segc[s1i] * acc[s1i], pv1 = segc[s1i] * temp;
      float s0 = (lane & 1) ? pv0 : pa0;
      float g0 = (lane & 1) ? pa0 : pv0;
      s0 += __shfl_xor(g0, 1, 64);
      float s1 = (lane & 1) ? pv1 : pa1;
      float g1 = (lane & 1) ? pa1 : pv1;
      s1 += __shfl_xor(g1, 1, 64);
      float cv = (lane & 2) ? s1 : s0;
      float gv = (lane & 2) ? s0 : s1;
      cv += __shfl_xor(gv, 2, 64);
      cv += __shfl_xor(cv, 4, 64);
      cv += __shfl_xor(cv, 8, 64);
      cv += __shfl_xor(cv, 16, 64);
      cv += __shfl_xor(cv, 32, 64);
      // lane 0: pa(k0g), lane 1: pv(k0g), lane 2: pa(k0g+1), lane 3: pv(k0g+1)
      const int k0g = kbase + 2 * pp;
      if (lane < 4) sRed[wv][2 * k0g + lane] = cv;
    }
  }

  __syncthreads();
  if (t < 2 * KK) {
    const float s = sRed[0][t] + sRed[1][t] + sRed[2][t] + sRed[3][t];
    const int tile = tcy * NT + tcx;
    const int k = t >> 1;
    float* dst = (t & 1) ? pV : pA;
    dst[(n * KK + k) * NTILES + tile] = s;  // [nk][tile]: coalesced for final1
  }
}

// ---------- K3a: per-nk tile reduction (160 blocks x 64 thr) ----------
__global__ void ncuts_final1(const float* __restrict__ pA, const float* __restrict__ pV,
                             float* __restrict__ rA, float* __restrict__ rV) {
  const int nk = blockIdx.x, t = threadIdx.x;
  float a = 0.f, v = 0.f;
  for (int j = t; j < NTILES; j += 64) {
    a += pA[nk * NTILES + j];
    v += pV[nk * NTILES + j];
  }
  #pragma unroll
  for (int m = 1; m < 64; m <<= 1) {
    a += __shfl_xor(a, m, 64);
    v += __shfl_xor(v, m, 64);
  }
  if (t == 0) { rA[nk] = a; rV[nk] = v; }
}

// ---------- K3b: divide + sum -> loss ----------
__global__ void ncuts_final2(const float* __restrict__ rA, const float* __restrict__ rV,
                             float* __restrict__ out) {
  __shared__ float red[256];
  const int t = threadIdx.x;
  float r = 0.f;
  if (t < NKTOT) r = rA[t] / rV[t];
  red[t] = r;
  __syncthreads();
  for (int s = 128; s > 0; s >>= 1) {
    if (t < s) red[t] += red[t + s];
    __syncthreads();
  }
  if (t == 0) out[0] = (float)NKTOT - red[0];
}

extern "C" void kernel_launch(void* const* d_in, const int* in_sizes, int n_in,
                              void* d_out, int out_size, void* d_ws, size_t ws_size,
                              hipStream_t stream) {
  const float* seg = (const float*)d_in[0];
  const float* x   = (const float*)d_in[1];
  float* ws   = (float*)d_ws;
  float* pA   = ws;                        // 160*196 floats
  float* pV   = ws + NKTOT * NTILES;       // 160*196 floats
  float* Sv   = ws + 2 * NKTOT * NTILES;   // 24
  float* s2v  = Sv + 24;                   // 8
  float* part = s2v + 8;                   // NB*SB*4 = 1024
  float* rA   = part + 1024;               // 160
  float* rV   = rA + NKTOT;                // 160

  ncuts_stats1<<<NB * SB, 256, 0, stream>>>(x, part);
  ncuts_stats2<<<1, 64, 0, stream>>>(part, Sv, s2v);
  dim3 grid(NT, NT, NB);
  ncuts_main<<<grid, 256, 0, stream>>>(seg, x, Sv, s2v, pA, pV);
  ncuts_final1<<<NKTOT, 64, 0, stream>>>(pA, pV, rA, rV);
  ncuts_final2<<<1, 256, 0, stream>>>(rA, rV, (float*)d_out);
}